// Round 23
// baseline (328.319 us; speedup 1.0000x reference)
//
#include <hip/hip_runtime.h>
#include <hip/hip_bf16.h>

#define NN 50000
#define EE 600000
#define RR 8
#define NSEG (NN*RR)                     // 400000
#define NB_SCAN ((NSEG + 1023)/1024)     // 391
#define RSTRIDE 2320                     // A-tile row stride in BYTES

typedef unsigned int u32;
typedef __attribute__((ext_vector_type(8))) short bf16x8;
typedef __attribute__((ext_vector_type(4))) float f32x4;
typedef __attribute__((ext_vector_type(2))) float f32x2;
typedef __attribute__((ext_vector_type(4))) u32 u32x4;

// fp32 -> bf16 round-to-nearest-even (finite inputs only)
__device__ inline unsigned short f2bf(float f){
  u32 u = __float_as_uint(f);
  u32 r = (u + 0x7fffu + ((u >> 16) & 1u)) >> 16;
  return (unsigned short)r;
}
__device__ inline float bf2f(unsigned short b){ return __uint_as_float((u32)b << 16); }

// ---------------- conversion: fp32 -> bf16, 4 elems/thread ----------------
__global__ void cvt_k(const float* __restrict__ in, unsigned short* __restrict__ out, int n4){
  int i = blockIdx.x * 256 + threadIdx.x;
  if (i >= n4) return;
  float4 v = ((const float4*)in)[i];
  ushort4 o;
  o.x = f2bf(v.x); o.y = f2bf(v.y); o.z = f2bf(v.z); o.w = f2bf(v.w);
  ((ushort4*)out)[i] = o;
}

// ---------------- pack ALL B stacks into MFMA fragment order ---------------
__global__ void packall_k(const float* __restrict__ W1, const float* __restrict__ r1,
                          const float* __restrict__ W2, const float* __restrict__ r2,
                          const float* __restrict__ W3, const float* __restrict__ r3,
                          const float* __restrict__ rw,
                          short* __restrict__ Bp1, short* __restrict__ Bp2,
                          short* __restrict__ Bp3, short* __restrict__ BpR){
  int tid = blockIdx.x * 256 + threadIdx.x;
  if (tid >= 112 * 512) return;
  int unit = tid >> 9;
  const float* Wrel; const float* root; short* Bp; int k32; int krel;
  if      (unit < 36){ Wrel = W1; root = r1; Bp = Bp1; k32 = unit;       krel = 1024; }
  else if (unit < 72){ Wrel = W2; root = r2; Bp = Bp2; k32 = unit - 36;  krel = 1024; }
  else if (unit <108){ Wrel = W3; root = r3; Bp = Bp3; k32 = unit - 72;  krel = 1024; }
  else               { Wrel = rw; root = rw; Bp = BpR; k32 = unit - 108; krel = 0;    }
  int lane = tid & 63;
  int nf   = (tid >> 6) & 7;
  int col  = nf * 16 + (lane & 15);
  short vals[8];
#pragma unroll
  for (int i = 0; i < 8; ++i){
    int kk = k32 * 32 + ((lane >> 4) << 3) + i;
    float f = (kk < krel) ? Wrel[(size_t)kk * 128 + col]
                          : root[(size_t)(kk - krel) * 128 + col];
    vals[i] = (short)f2bf(f);
  }
  *(bf16x8*)(Bp + (size_t)(k32 * 512 + (tid & 511)) * 8) = *(const bf16x8*)vals;
}

// ---------------- CSR build (relation-major: seg = r*NN + dst) -------------
__global__ void count_k(const int* __restrict__ dst, const int* __restrict__ et,
                        u32* __restrict__ cnt){
  int e = blockIdx.x * 256 + threadIdx.x;
  if (e >= EE) return;
  atomicAdd(&cnt[(size_t)et[e] * NN + dst[e]], 1u);
}

__global__ void scan1_k(const u32* __restrict__ cnt, u32* __restrict__ offs, u32* __restrict__ bsum){
  __shared__ u32 s[512];
  int t = threadIdx.x;                       // 256 threads
  int base = blockIdx.x * 1024 + t * 4;
  u32 loc[4]; u32 sum = 0;
#pragma unroll
  for (int i = 0; i < 4; ++i){ loc[i] = (base + i < NSEG) ? cnt[base + i] : 0u; sum += loc[i]; }
  int pb = 0;
  s[t] = sum; __syncthreads();
  for (int off = 1; off < 256; off <<= 1){
    u32 v = s[pb * 256 + t];
    if (t >= off) v += s[pb * 256 + t - off];
    s[(pb ^ 1) * 256 + t] = v; pb ^= 1; __syncthreads();
  }
  u32 incl = s[pb * 256 + t];
  u32 excl = incl - sum;
  if (t == 255) bsum[blockIdx.x] = incl;
  u32 run = excl;
#pragma unroll
  for (int i = 0; i < 4; ++i){ if (base + i < NSEG) offs[base + i] = run; run += loc[i]; }
}

__global__ void scan2_k(u32* __restrict__ bsum){
  __shared__ u32 s[1024];
  int t = threadIdx.x;                       // 512 threads
  u32 v = (t < NB_SCAN) ? bsum[t] : 0u;
  int pb = 0;
  s[t] = v; __syncthreads();
  for (int off = 1; off < 512; off <<= 1){
    u32 x = s[pb * 512 + t];
    if (t >= off) x += s[pb * 512 + t - off];
    s[(pb ^ 1) * 512 + t] = x; pb ^= 1; __syncthreads();
  }
  u32 incl = s[pb * 512 + t];
  if (t < NB_SCAN) bsum[t] = incl - v;       // exclusive
}

__global__ void scan3_k(u32* __restrict__ offs, const u32* __restrict__ bsum){
  int t = threadIdx.x;
  int base = blockIdx.x * 1024 + t * 4;
  u32 add = bsum[blockIdx.x];
#pragma unroll
  for (int i = 0; i < 4; ++i){ if (base + i < NSEG) offs[base + i] += add; }
  if (blockIdx.x == 0 && t == 0) offs[NSEG] = EE;
}

// fill: reuse cnt as cursor (atomicSub)
__global__ void fill_k(const int* __restrict__ src, const int* __restrict__ dst,
                       const int* __restrict__ et, const u32* __restrict__ offs,
                       u32* __restrict__ cnt, int* __restrict__ elist){
  int e = blockIdx.x * 256 + threadIdx.x;
  if (e >= EE) return;
  int s = et[e] * NN + dst[e];
  u32 p = atomicSub(&cnt[s], 1u);
  elist[offs[s] + p - 1] = src[e];
}

// ---------------- res projection: resb = bf16(x @ res_w + res_b) ----------
__launch_bounds__(256, 4)
__global__ void resg_k(const unsigned short* __restrict__ xb, const short* __restrict__ Bp,
                       const float* __restrict__ rb, unsigned short* __restrict__ resb){
  const int tid = threadIdx.x;
  const int w = tid >> 6, l = tid & 63;
  const int sub = l >> 4, llr = l & 15;
  const int rowbase = blockIdx.x * 64 + w * 16;
  int vr = rowbase + llr; if (vr > NN - 1) vr = NN - 1;
  f32x4 acc[8] = {};
#pragma unroll
  for (int t = 0; t < 4; ++t){
    bf16x8 af = *(const bf16x8*)(xb + (size_t)vr * 128 + (t * 4 + sub) * 8);
    const short* bb = Bp + (size_t)(t * 8) * 512 + l * 8;
#pragma unroll
    for (int nf = 0; nf < 8; ++nf){
      bf16x8 bq = *(const bf16x8*)(bb + nf * 512);
      acc[nf] = __builtin_amdgcn_mfma_f32_16x16x32_bf16(af, bq, acc[nf], 0, 0, 0);
    }
  }
  const int lr = l >> 4, lc = l & 15;
#pragma unroll
  for (int nf = 0; nf < 8; ++nf){
    int col = nf * 16 + lc;
    float bv = rb[col];
#pragma unroll
    for (int r = 0; r < 4; ++r){
      int row = rowbase + lr * 4 + r;
      if (row < NN) resb[(size_t)row * 128 + col] = f2bf(acc[nf][r] + bv);
    }
  }
}

// ---- per-segment gather with 4-wide edge batching, packed f32x2 adds ------
#define ACC1(P0, P1) do{ \
  _Pragma("unroll") \
  for (int i_ = 0; i_ < 4; ++i_){ \
    f32x2 a_, b_; \
    a_[0] = __uint_as_float((P0)[i_] << 16); \
    a_[1] = __uint_as_float((P0)[i_] & 0xffff0000u); \
    b_[0] = __uint_as_float((P1)[i_] << 16); \
    b_[1] = __uint_as_float((P1)[i_] & 0xffff0000u); \
    s0[i_] += a_; s1[i_] += b_; \
  } }while(0)

__device__ __forceinline__ void gather_seg(u32 beg, u32 end,
                                           const unsigned short* __restrict__ hb,
                                           const int* __restrict__ elist,
                                           char* __restrict__ Ab,
                                           int row, int rseg, int ll8){
  f32x2 s0[4], s1[4];
#pragma unroll
  for (int i = 0; i < 4; ++i){ s0[i] = (f32x2){0.f,0.f}; s1[i] = (f32x2){0.f,0.f}; }
  u32 e = beg;
  for (; e + 4 <= end; e += 4){
    int q0 = elist[e], q1 = elist[e+1], q2 = elist[e+2], q3 = elist[e+3];
    const unsigned short* r0 = hb + (size_t)q0 * 128;
    const unsigned short* r1 = hb + (size_t)q1 * 128;
    const unsigned short* r2 = hb + (size_t)q2 * 128;
    const unsigned short* r3 = hb + (size_t)q3 * 128;
    u32x4 p00 = *(const u32x4*)r0, p01 = *(const u32x4*)(r0 + 8);
    u32x4 p10 = *(const u32x4*)r1, p11 = *(const u32x4*)(r1 + 8);
    u32x4 p20 = *(const u32x4*)r2, p21 = *(const u32x4*)(r2 + 8);
    u32x4 p30 = *(const u32x4*)r3, p31 = *(const u32x4*)(r3 + 8);
    ACC1(p00, p01); ACC1(p10, p11); ACC1(p20, p21); ACC1(p30, p31);
  }
  if (e + 2 <= end){
    int q0 = elist[e], q1 = elist[e+1];
    const unsigned short* r0 = hb + (size_t)q0 * 128;
    const unsigned short* r1 = hb + (size_t)q1 * 128;
    u32x4 p00 = *(const u32x4*)r0, p01 = *(const u32x4*)(r0 + 8);
    u32x4 p10 = *(const u32x4*)r1, p11 = *(const u32x4*)(r1 + 8);
    ACC1(p00, p01); ACC1(p10, p11);
    e += 2;
  }
  if (e < end){
    int q0 = elist[e];
    const unsigned short* r0 = hb + (size_t)q0 * 128;
    u32x4 p00 = *(const u32x4*)r0, p01 = *(const u32x4*)(r0 + 8);
    ACC1(p00, p01);
  }
  u32 deg = end - beg;
  if (deg){
    float inv = __builtin_amdgcn_rcpf((float)deg);
#pragma unroll
    for (int i = 0; i < 4; ++i){ s0[i] *= inv; s1[i] *= inv; }
  }
  u32x4 o0, o1;
#pragma unroll
  for (int i = 0; i < 4; ++i){
    o0[i] = (u32)f2bf(s0[i][0]) | ((u32)f2bf(s0[i][1]) << 16);
    o1[i] = (u32)f2bf(s1[i][0]) | ((u32)f2bf(s1[i][1]) << 16);
  }
  char* wp = Ab + row * RSTRIDE + (rseg * 16 + ll8 * 2) * 16;
  *(u32x4*)wp = o0;
  *(u32x4*)(wp + 16) = o1;
}

// -------- FUSED layer: gather->LDS A-tile (K=1152) -> barrier -> GEMM -------
// 1024 threads, BM=32. A-tile [32 rows][RSTRIDE] = 72.5 KB (2 blk/CU).
// Phase 1: 128 8-lane groups x 2 segments, 4-wide edge batching; groups 0-31
// copy the root row.
// Phase 2: 4 WAVES ONLY — wave w=nq owns nf pair {2nq,2nq+1} x BOTH mf tiles:
// per (kt,t): 2 B loads + 2 ds_reads + 4 MFMAs. Each B-frag is loaded exactly
// ONCE per block (B-L2 traffic halved vs R22: 900->450 MB/layer). Waves 4-15
// retire after gather, freeing SIMDs for other blocks' gather phases.
template<int OUTMODE>
__launch_bounds__(1024, 8)
__global__ void fused_k(const u32* __restrict__ offs, const int* __restrict__ elist,
                        const unsigned short* __restrict__ h,
                        const short* __restrict__ Bp,
                        const float* __restrict__ bias,
                        const unsigned short* __restrict__ resb,
                        float* __restrict__ outf, unsigned short* __restrict__ outb){
  __shared__ char Ab[32 * RSTRIDE];          // 72.5 KB
  const int tid = threadIdx.x;
  const int mbase = blockIdx.x * 32;

  // ---------- phase 1: gather ----------
  {
    const int g = tid >> 3, ll8 = tid & 7;
    const unsigned short* hb = h + (size_t)ll8 * 16;
    int r0 = g >> 5, row0 = g & 31;
    int t1 = g + 128;
    int r1 = t1 >> 5, row1 = t1 & 31;
    int v0 = mbase + row0; if (v0 > NN - 1) v0 = NN - 1;
    int v1 = mbase + row1; if (v1 > NN - 1) v1 = NN - 1;
    size_t sg0 = (size_t)r0 * NN + v0, sg1 = (size_t)r1 * NN + v1;
    u32 b0 = offs[sg0], e0 = offs[sg0 + 1];
    u32 b1 = offs[sg1], e1 = offs[sg1 + 1];
    gather_seg(b0, e0, hb, elist, Ab, row0, r0, ll8);
    gather_seg(b1, e1, hb, elist, Ab, row1, r1, ll8);
    if (g < 32){                             // root row copy, slots 128..143
      int row = g;
      int v = mbase + row; if (v > NN - 1) v = NN - 1;
      const unsigned short* rp = h + (size_t)v * 128 + ll8 * 16;
      u32x4 o0 = *(const u32x4*)rp, o1 = *(const u32x4*)(rp + 8);
      char* wp = Ab + row * RSTRIDE + (128 + ll8 * 2) * 16;
      *(u32x4*)wp = o0;
      *(u32x4*)(wp + 16) = o1;
    }
  }
  __syncthreads();

  // ---------- phase 2: GEMM (4 waves; waves 4-15 done) ----------
  const int w = tid >> 6, l = tid & 63;
  if (w >= 4) return;
  const int nq = w;
  const int nf0 = nq * 2, nf1 = nq * 2 + 1;
  const int sub = l >> 4, llr = l & 15;
  f32x4 acc00 = {}, acc01 = {}, acc10 = {}, acc11 = {};
#pragma unroll 6
  for (int kt = 0; kt < 18; ++kt){
#pragma unroll
    for (int t = 0; t < 2; ++t){
      int ks = kt * 8 + t * 4 + sub;
      bf16x8 af0 = *(const bf16x8*)(Ab + llr * RSTRIDE        + ks * 16);
      bf16x8 af1 = *(const bf16x8*)(Ab + (16 + llr) * RSTRIDE + ks * 16);
      const short* bb = Bp + ((size_t)((kt * 2 + t) * 8)) * 512 + l * 8;
      bf16x8 bq0 = *(const bf16x8*)(bb + nf0 * 512);
      bf16x8 bq1 = *(const bf16x8*)(bb + nf1 * 512);
      acc00 = __builtin_amdgcn_mfma_f32_16x16x32_bf16(af0, bq0, acc00, 0, 0, 0);
      acc01 = __builtin_amdgcn_mfma_f32_16x16x32_bf16(af0, bq1, acc01, 0, 0, 0);
      acc10 = __builtin_amdgcn_mfma_f32_16x16x32_bf16(af1, bq0, acc10, 0, 0, 0);
      acc11 = __builtin_amdgcn_mfma_f32_16x16x32_bf16(af1, bq1, acc11, 0, 0, 0);
    }
  }

  // ---------- epilogue ----------
  const int lr = l >> 4, lc = l & 15;
#pragma unroll
  for (int mf = 0; mf < 2; ++mf){
#pragma unroll
    for (int half = 0; half < 2; ++half){
      int col = (half ? nf1 : nf0) * 16 + lc;
      float bv = bias[col];
      const f32x4& ac = mf ? (half ? acc11 : acc10) : (half ? acc01 : acc00);
#pragma unroll
      for (int r = 0; r < 4; ++r){
        int row = mbase + mf * 16 + lr * 4 + r;
        if (row < NN){
          float v = ac[r] + bv;
          v = bf2f(resb[(size_t)row * 128 + col]) + fmaxf(v, 0.f);
          if (OUTMODE == 1) outb[(size_t)row * 128 + col] = f2bf(v);
          else              outf[(size_t)row * 128 + col] = v;
        }
      }
    }
  }
}

extern "C" void kernel_launch(void* const* d_in, const int* in_sizes, int n_in,
                              void* d_out, int out_size, void* d_ws, size_t ws_size,
                              hipStream_t stream){
  const float* x  = (const float*)d_in[0];
  const int*   ei = (const int*)d_in[1];
  const int*   et = (const int*)d_in[2];
  const float* W1 = (const float*)d_in[3];
  const float* r1 = (const float*)d_in[4];
  const float* b1 = (const float*)d_in[5];
  const float* W2 = (const float*)d_in[6];
  const float* r2 = (const float*)d_in[7];
  const float* b2 = (const float*)d_in[8];
  const float* W3 = (const float*)d_in[9];
  const float* r3 = (const float*)d_in[10];
  const float* b3 = (const float*)d_in[11];
  const float* rw = (const float*)d_in[12];
  const float* rb = (const float*)d_in[13];
  const int* srcv = ei;
  const int* dstv = ei + EE;

  char* p = (char*)d_ws;
  auto take = [&](size_t b)->char*{ char* q = p; p += (b + 255) & ~(size_t)255; return q; };
  unsigned short* xb   = (unsigned short*)take((size_t)NN * 128 * 2);
  unsigned short* h1   = (unsigned short*)take((size_t)NN * 128 * 2);
  unsigned short* h2   = (unsigned short*)take((size_t)NN * 128 * 2);
  unsigned short* resb = (unsigned short*)take((size_t)NN * 128 * 2);
  short* Bp1 = (short*)take(36 * 4096 * 2);
  short* Bp2 = (short*)take(36 * 4096 * 2);
  short* Bp3 = (short*)take(36 * 4096 * 2);
  short* BpR = (short*)take(4 * 4096 * 2);
  u32* cnt   = (u32*)take((size_t)NSEG * 4);
  u32* offs  = (u32*)take((size_t)(NSEG + 1) * 4);
  int* elist = (int*)take((size_t)EE * 4);
  u32* bsum  = (u32*)take((size_t)NB_SCAN * 4);

  hipMemsetAsync(cnt, 0, (size_t)NSEG * 4, stream);

  // conversions + weight packing (once)
  cvt_k<<<(NN * 128 / 4 + 255) / 256, 256, 0, stream>>>(x, xb, NN * 128 / 4);
  packall_k<<<(112 * 512 + 255) / 256, 256, 0, stream>>>(W1, r1, W2, r2, W3, r3, rw,
                                                         Bp1, Bp2, Bp3, BpR);

  // CSR over segments (etype*NN + dst), once for all layers
  count_k<<<(EE + 255) / 256, 256, 0, stream>>>(dstv, et, cnt);
  scan1_k<<<NB_SCAN, 256, 0, stream>>>(cnt, offs, bsum);
  scan2_k<<<1, 512, 0, stream>>>(bsum);
  scan3_k<<<NB_SCAN, 256, 0, stream>>>(offs, bsum);
  fill_k<<<(EE + 255) / 256, 256, 0, stream>>>(srcv, dstv, et, offs, cnt, elist);

  const int GB = (NN + 31) / 32;  // 1563

  // res = bf16(x @ res_w + res_b)
  resg_k<<<(NN + 63) / 64, 256, 0, stream>>>(xb, BpR, rb, resb);

  // fused layers
  fused_k<1><<<GB, 1024, 0, stream>>>(offs, elist, xb, Bp1, b1, resb, nullptr, h1);
  fused_k<1><<<GB, 1024, 0, stream>>>(offs, elist, h1, Bp2, b2, resb, nullptr, h2);
  fused_k<2><<<GB, 1024, 0, stream>>>(offs, elist, h2, Bp3, b3, resb, (float*)d_out, nullptr);
}

// Round 24
// 285.070 us; speedup vs baseline: 1.1517x; 1.1517x over previous
//
#include <hip/hip_runtime.h>
#include <hip/hip_bf16.h>

#define NN 50000
#define EE 600000
#define RR 8
#define NSEG (NN*RR)                     // 400000
#define NB_SCAN ((NSEG + 1023)/1024)     // 391
#define RSTRIDE 2320                     // A-tile row stride in BYTES (145 16B slots)

typedef unsigned int u32;
typedef __attribute__((ext_vector_type(8))) short bf16x8;
typedef __attribute__((ext_vector_type(4))) float f32x4;
typedef __attribute__((ext_vector_type(2))) float f32x2;
typedef __attribute__((ext_vector_type(4))) u32 u32x4;

// fp32 -> bf16 round-to-nearest-even (finite inputs only)
__device__ inline unsigned short f2bf(float f){
  u32 u = __float_as_uint(f);
  u32 r = (u + 0x7fffu + ((u >> 16) & 1u)) >> 16;
  return (unsigned short)r;
}
__device__ inline float bf2f(unsigned short b){ return __uint_as_float((u32)b << 16); }

// ---------------- conversion: fp32 -> bf16, 4 elems/thread ----------------
__global__ void cvt_k(const float* __restrict__ in, unsigned short* __restrict__ out, int n4){
  int i = blockIdx.x * 256 + threadIdx.x;
  if (i >= n4) return;
  float4 v = ((const float4*)in)[i];
  ushort4 o;
  o.x = f2bf(v.x); o.y = f2bf(v.y); o.z = f2bf(v.z); o.w = f2bf(v.w);
  ((ushort4*)out)[i] = o;
}

// ---------------- pack ALL B stacks into MFMA fragment order ---------------
__global__ void packall_k(const float* __restrict__ W1, const float* __restrict__ r1,
                          const float* __restrict__ W2, const float* __restrict__ r2,
                          const float* __restrict__ W3, const float* __restrict__ r3,
                          const float* __restrict__ rw,
                          short* __restrict__ Bp1, short* __restrict__ Bp2,
                          short* __restrict__ Bp3, short* __restrict__ BpR){
  int tid = blockIdx.x * 256 + threadIdx.x;
  if (tid >= 112 * 512) return;
  int unit = tid >> 9;
  const float* Wrel; const float* root; short* Bp; int k32; int krel;
  if      (unit < 36){ Wrel = W1; root = r1; Bp = Bp1; k32 = unit;       krel = 1024; }
  else if (unit < 72){ Wrel = W2; root = r2; Bp = Bp2; k32 = unit - 36;  krel = 1024; }
  else if (unit <108){ Wrel = W3; root = r3; Bp = Bp3; k32 = unit - 72;  krel = 1024; }
  else               { Wrel = rw; root = rw; Bp = BpR; k32 = unit - 108; krel = 0;    }
  int lane = tid & 63;
  int nf   = (tid >> 6) & 7;
  int col  = nf * 16 + (lane & 15);
  short vals[8];
#pragma unroll
  for (int i = 0; i < 8; ++i){
    int kk = k32 * 32 + ((lane >> 4) << 3) + i;
    float f = (kk < krel) ? Wrel[(size_t)kk * 128 + col]
                          : root[(size_t)(kk - krel) * 128 + col];
    vals[i] = (short)f2bf(f);
  }
  *(bf16x8*)(Bp + (size_t)(k32 * 512 + (tid & 511)) * 8) = *(const bf16x8*)vals;
}

// ---------------- CSR build (relation-major: seg = r*NN + dst) -------------
__global__ void count_k(const int* __restrict__ dst, const int* __restrict__ et,
                        u32* __restrict__ cnt){
  int e = blockIdx.x * 256 + threadIdx.x;
  if (e >= EE) return;
  atomicAdd(&cnt[(size_t)et[e] * NN + dst[e]], 1u);
}

__global__ void scan1_k(const u32* __restrict__ cnt, u32* __restrict__ offs, u32* __restrict__ bsum){
  __shared__ u32 s[512];
  int t = threadIdx.x;                       // 256 threads
  int base = blockIdx.x * 1024 + t * 4;
  u32 loc[4]; u32 sum = 0;
#pragma unroll
  for (int i = 0; i < 4; ++i){ loc[i] = (base + i < NSEG) ? cnt[base + i] : 0u; sum += loc[i]; }
  int pb = 0;
  s[t] = sum; __syncthreads();
  for (int off = 1; off < 256; off <<= 1){
    u32 v = s[pb * 256 + t];
    if (t >= off) v += s[pb * 256 + t - off];
    s[(pb ^ 1) * 256 + t] = v; pb ^= 1; __syncthreads();
  }
  u32 incl = s[pb * 256 + t];
  u32 excl = incl - sum;
  if (t == 255) bsum[blockIdx.x] = incl;
  u32 run = excl;
#pragma unroll
  for (int i = 0; i < 4; ++i){ if (base + i < NSEG) offs[base + i] = run; run += loc[i]; }
}

__global__ void scan2_k(u32* __restrict__ bsum){
  __shared__ u32 s[1024];
  int t = threadIdx.x;                       // 512 threads
  u32 v = (t < NB_SCAN) ? bsum[t] : 0u;
  int pb = 0;
  s[t] = v; __syncthreads();
  for (int off = 1; off < 512; off <<= 1){
    u32 x = s[pb * 512 + t];
    if (t >= off) x += s[pb * 512 + t - off];
    s[(pb ^ 1) * 512 + t] = x; pb ^= 1; __syncthreads();
  }
  u32 incl = s[pb * 512 + t];
  if (t < NB_SCAN) bsum[t] = incl - v;       // exclusive
}

__global__ void scan3_k(u32* __restrict__ offs, const u32* __restrict__ bsum){
  int t = threadIdx.x;
  int base = blockIdx.x * 1024 + t * 4;
  u32 add = bsum[blockIdx.x];
#pragma unroll
  for (int i = 0; i < 4; ++i){ if (base + i < NSEG) offs[base + i] += add; }
  if (blockIdx.x == 0 && t == 0) offs[NSEG] = EE;
}

// fill: reuse cnt as cursor (atomicSub)
__global__ void fill_k(const int* __restrict__ src, const int* __restrict__ dst,
                       const int* __restrict__ et, const u32* __restrict__ offs,
                       u32* __restrict__ cnt, int* __restrict__ elist){
  int e = blockIdx.x * 256 + threadIdx.x;
  if (e >= EE) return;
  int s = et[e] * NN + dst[e];
  u32 p = atomicSub(&cnt[s], 1u);
  elist[offs[s] + p - 1] = src[e];
}

// ---------------- res projection: resb = bf16(x @ res_w + res_b) ----------
__launch_bounds__(256, 4)
__global__ void resg_k(const unsigned short* __restrict__ xb, const short* __restrict__ Bp,
                       const float* __restrict__ rb, unsigned short* __restrict__ resb){
  const int tid = threadIdx.x;
  const int w = tid >> 6, l = tid & 63;
  const int sub = l >> 4, llr = l & 15;
  const int rowbase = blockIdx.x * 64 + w * 16;
  int vr = rowbase + llr; if (vr > NN - 1) vr = NN - 1;
  f32x4 acc[8] = {};
#pragma unroll
  for (int t = 0; t < 4; ++t){
    bf16x8 af = *(const bf16x8*)(xb + (size_t)vr * 128 + (t * 4 + sub) * 8);
    const short* bb = Bp + (size_t)(t * 8) * 512 + l * 8;
#pragma unroll
    for (int nf = 0; nf < 8; ++nf){
      bf16x8 bq = *(const bf16x8*)(bb + nf * 512);
      acc[nf] = __builtin_amdgcn_mfma_f32_16x16x32_bf16(af, bq, acc[nf], 0, 0, 0);
    }
  }
  const int lr = l >> 4, lc = l & 15;
#pragma unroll
  for (int nf = 0; nf < 8; ++nf){
    int col = nf * 16 + lc;
    float bv = rb[col];
#pragma unroll
    for (int r = 0; r < 4; ++r){
      int row = rowbase + lr * 4 + r;
      if (row < NN) resb[(size_t)row * 128 + col] = f2bf(acc[nf][r] + bv);
    }
  }
}

// ---- per-segment gather with 4-wide edge batching, packed f32x2 adds ------
#define ACC1(P0, P1) do{ \
  _Pragma("unroll") \
  for (int i_ = 0; i_ < 4; ++i_){ \
    f32x2 a_, b_; \
    a_[0] = __uint_as_float((P0)[i_] << 16); \
    a_[1] = __uint_as_float((P0)[i_] & 0xffff0000u); \
    b_[0] = __uint_as_float((P1)[i_] << 16); \
    b_[1] = __uint_as_float((P1)[i_] & 0xffff0000u); \
    s0[i_] += a_; s1[i_] += b_; \
  } }while(0)

__device__ __forceinline__ void gather_seg(u32 beg, u32 end,
                                           const unsigned short* __restrict__ hb,
                                           const int* __restrict__ elist,
                                           char* __restrict__ Ab,
                                           int row, int rseg, int ll8){
  f32x2 s0[4], s1[4];
#pragma unroll
  for (int i = 0; i < 4; ++i){ s0[i] = (f32x2){0.f,0.f}; s1[i] = (f32x2){0.f,0.f}; }
  u32 e = beg;
  for (; e + 4 <= end; e += 4){
    int q0 = elist[e], q1 = elist[e+1], q2 = elist[e+2], q3 = elist[e+3];
    const unsigned short* r0 = hb + (size_t)q0 * 128;
    const unsigned short* r1 = hb + (size_t)q1 * 128;
    const unsigned short* r2 = hb + (size_t)q2 * 128;
    const unsigned short* r3 = hb + (size_t)q3 * 128;
    u32x4 p00 = *(const u32x4*)r0, p01 = *(const u32x4*)(r0 + 8);
    u32x4 p10 = *(const u32x4*)r1, p11 = *(const u32x4*)(r1 + 8);
    u32x4 p20 = *(const u32x4*)r2, p21 = *(const u32x4*)(r2 + 8);
    u32x4 p30 = *(const u32x4*)r3, p31 = *(const u32x4*)(r3 + 8);
    ACC1(p00, p01); ACC1(p10, p11); ACC1(p20, p21); ACC1(p30, p31);
  }
  if (e + 2 <= end){
    int q0 = elist[e], q1 = elist[e+1];
    const unsigned short* r0 = hb + (size_t)q0 * 128;
    const unsigned short* r1 = hb + (size_t)q1 * 128;
    u32x4 p00 = *(const u32x4*)r0, p01 = *(const u32x4*)(r0 + 8);
    u32x4 p10 = *(const u32x4*)r1, p11 = *(const u32x4*)(r1 + 8);
    ACC1(p00, p01); ACC1(p10, p11);
    e += 2;
  }
  if (e < end){
    int q0 = elist[e];
    const unsigned short* r0 = hb + (size_t)q0 * 128;
    u32x4 p00 = *(const u32x4*)r0, p01 = *(const u32x4*)(r0 + 8);
    ACC1(p00, p01);
  }
  u32 deg = end - beg;
  if (deg){
    float inv = __builtin_amdgcn_rcpf((float)deg);
#pragma unroll
    for (int i = 0; i < 4; ++i){ s0[i] *= inv; s1[i] *= inv; }
  }
  u32x4 o0, o1;
#pragma unroll
  for (int i = 0; i < 4; ++i){
    o0[i] = (u32)f2bf(s0[i][0]) | ((u32)f2bf(s0[i][1]) << 16);
    o1[i] = (u32)f2bf(s1[i][0]) | ((u32)f2bf(s1[i][1]) << 16);
  }
  char* wp = Ab + row * RSTRIDE + (rseg * 16 + ll8 * 2) * 16;
  *(u32x4*)wp = o0;
  *(u32x4*)(wp + 16) = o1;
}

// -------- FUSED layer: BM=16, 512 threads, 4 BLOCKS/CU ---------------------
// LDS = 16 x 2320 B = 36.25 KB -> 4 resident blocks/CU (2x R19's gather
// concurrency; full 2048-thread occupancy). NN = 3125*16 -> no row clamps.
// Phase 1: 64 8-lane groups x 2 segments (tasks g and g+64: same row,
// relations r and r+4); groups 0-15 copy the root row.
// Phase 2: 8 waves, wave w=nf owns 16 rows x 16 cols: 1 ds_read + 1 B load
// + 1 MFMA per (kt,t), 36 MFMA total, no barriers.
template<int OUTMODE>
__launch_bounds__(512, 4)
__global__ void fused_k(const u32* __restrict__ offs, const int* __restrict__ elist,
                        const unsigned short* __restrict__ h,
                        const short* __restrict__ Bp,
                        const float* __restrict__ bias,
                        const unsigned short* __restrict__ resb,
                        float* __restrict__ outf, unsigned short* __restrict__ outb){
  __shared__ char Ab[16 * RSTRIDE];          // 36.25 KB
  const int tid = threadIdx.x;
  const int mbase = blockIdx.x * 16;

  // ---------- phase 1: gather ----------
  {
    const int g = tid >> 3, ll8 = tid & 7;
    const unsigned short* hb = h + (size_t)ll8 * 16;
    int r0 = g >> 4, row = g & 15;           // task0: relation r0, row
    int r1 = r0 + 4;                         // task1: relation r0+4, same row
    int v = mbase + row;                     // always < NN (3125*16 exact)
    size_t sg0 = (size_t)r0 * NN + v, sg1 = (size_t)r1 * NN + v;
    u32 b0 = offs[sg0], e0 = offs[sg0 + 1];
    u32 b1 = offs[sg1], e1 = offs[sg1 + 1];
    gather_seg(b0, e0, hb, elist, Ab, row, r0, ll8);
    gather_seg(b1, e1, hb, elist, Ab, row, r1, ll8);
    if (g < 16){                             // root row copy, slots 128..143
      const unsigned short* rp = h + (size_t)(mbase + g) * 128 + ll8 * 16;
      u32x4 o0 = *(const u32x4*)rp, o1 = *(const u32x4*)(rp + 8);
      char* wp = Ab + g * RSTRIDE + (128 + ll8 * 2) * 16;
      *(u32x4*)wp = o0;
      *(u32x4*)(wp + 16) = o1;
    }
  }
  __syncthreads();

  // ---------- phase 2: GEMM (8 waves) ----------
  const int w = tid >> 6, l = tid & 63;
  const int nf = w;
  const int sub = l >> 4, llr = l & 15;
  f32x4 acc = {};
#pragma unroll 6
  for (int kt = 0; kt < 18; ++kt){
#pragma unroll
    for (int t = 0; t < 2; ++t){
      int ks = kt * 8 + t * 4 + sub;
      bf16x8 af = *(const bf16x8*)(Ab + llr * RSTRIDE + ks * 16);
      bf16x8 bq = *(const bf16x8*)(Bp + ((size_t)((kt * 2 + t) * 8 + nf)) * 512 + l * 8);
      acc = __builtin_amdgcn_mfma_f32_16x16x32_bf16(af, bq, acc, 0, 0, 0);
    }
  }

  // ---------- epilogue ----------
  const int lr = l >> 4, lc = l & 15;
  int col = nf * 16 + lc;
  float bv = bias[col];
#pragma unroll
  for (int r = 0; r < 4; ++r){
    int row = mbase + lr * 4 + r;
    float v = acc[r] + bv;
    v = bf2f(resb[(size_t)row * 128 + col]) + fmaxf(v, 0.f);
    if (OUTMODE == 1) outb[(size_t)row * 128 + col] = f2bf(v);
    else              outf[(size_t)row * 128 + col] = v;
  }
}

extern "C" void kernel_launch(void* const* d_in, const int* in_sizes, int n_in,
                              void* d_out, int out_size, void* d_ws, size_t ws_size,
                              hipStream_t stream){
  const float* x  = (const float*)d_in[0];
  const int*   ei = (const int*)d_in[1];
  const int*   et = (const int*)d_in[2];
  const float* W1 = (const float*)d_in[3];
  const float* r1 = (const float*)d_in[4];
  const float* b1 = (const float*)d_in[5];
  const float* W2 = (const float*)d_in[6];
  const float* r2 = (const float*)d_in[7];
  const float* b2 = (const float*)d_in[8];
  const float* W3 = (const float*)d_in[9];
  const float* r3 = (const float*)d_in[10];
  const float* b3 = (const float*)d_in[11];
  const float* rw = (const float*)d_in[12];
  const float* rb = (const float*)d_in[13];
  const int* srcv = ei;
  const int* dstv = ei + EE;

  char* p = (char*)d_ws;
  auto take = [&](size_t b)->char*{ char* q = p; p += (b + 255) & ~(size_t)255; return q; };
  unsigned short* xb   = (unsigned short*)take((size_t)NN * 128 * 2);
  unsigned short* h1   = (unsigned short*)take((size_t)NN * 128 * 2);
  unsigned short* h2   = (unsigned short*)take((size_t)NN * 128 * 2);
  unsigned short* resb = (unsigned short*)take((size_t)NN * 128 * 2);
  short* Bp1 = (short*)take(36 * 4096 * 2);
  short* Bp2 = (short*)take(36 * 4096 * 2);
  short* Bp3 = (short*)take(36 * 4096 * 2);
  short* BpR = (short*)take(4 * 4096 * 2);
  u32* cnt   = (u32*)take((size_t)NSEG * 4);
  u32* offs  = (u32*)take((size_t)(NSEG + 1) * 4);
  int* elist = (int*)take((size_t)EE * 4);
  u32* bsum  = (u32*)take((size_t)NB_SCAN * 4);

  hipMemsetAsync(cnt, 0, (size_t)NSEG * 4, stream);

  // conversions + weight packing (once)
  cvt_k<<<(NN * 128 / 4 + 255) / 256, 256, 0, stream>>>(x, xb, NN * 128 / 4);
  packall_k<<<(112 * 512 + 255) / 256, 256, 0, stream>>>(W1, r1, W2, r2, W3, r3, rw,
                                                         Bp1, Bp2, Bp3, BpR);

  // CSR over segments (etype*NN + dst), once for all layers
  count_k<<<(EE + 255) / 256, 256, 0, stream>>>(dstv, et, cnt);
  scan1_k<<<NB_SCAN, 256, 0, stream>>>(cnt, offs, bsum);
  scan2_k<<<1, 512, 0, stream>>>(bsum);
  scan3_k<<<NB_SCAN, 256, 0, stream>>>(offs, bsum);
  fill_k<<<(EE + 255) / 256, 256, 0, stream>>>(srcv, dstv, et, offs, cnt, elist);

  const int GB = NN / 16;  // 3125

  // res = bf16(x @ res_w + res_b)
  resg_k<<<(NN + 63) / 64, 256, 0, stream>>>(xb, BpR, rb, resb);

  // fused layers
  fused_k<1><<<GB, 512, 0, stream>>>(offs, elist, xb, Bp1, b1, resb, nullptr, h1);
  fused_k<1><<<GB, 512, 0, stream>>>(offs, elist, h1, Bp2, b2, resb, nullptr, h2);
  fused_k<2><<<GB, 512, 0, stream>>>(offs, elist, h2, Bp3, b3, resb, (float*)d_out, nullptr);
}

// Round 25
// 281.566 us; speedup vs baseline: 1.1660x; 1.0124x over previous
//
#include <hip/hip_runtime.h>
#include <hip/hip_bf16.h>

#define NN 50000
#define EE 600000
#define RR 8
#define NSEG (NN*RR)                     // 400000
#define NB_SCAN ((NSEG + 1023)/1024)     // 391
#define RSTRIDE 2320                     // A-tile row stride in BYTES (145 16B slots)

typedef unsigned int u32;
typedef __attribute__((ext_vector_type(8))) short bf16x8;
typedef __attribute__((ext_vector_type(4))) float f32x4;
typedef __attribute__((ext_vector_type(2))) float f32x2;
typedef __attribute__((ext_vector_type(4))) u32 u32x4;

// fp32 -> bf16 round-to-nearest-even (finite inputs only)
__device__ inline unsigned short f2bf(float f){
  u32 u = __float_as_uint(f);
  u32 r = (u + 0x7fffu + ((u >> 16) & 1u)) >> 16;
  return (unsigned short)r;
}
__device__ inline float bf2f(unsigned short b){ return __uint_as_float((u32)b << 16); }

// ---------------- pack ALL B stacks into MFMA fragment order ---------------
__global__ void packall_k(const float* __restrict__ W1, const float* __restrict__ r1,
                          const float* __restrict__ W2, const float* __restrict__ r2,
                          const float* __restrict__ W3, const float* __restrict__ r3,
                          const float* __restrict__ rw,
                          short* __restrict__ Bp1, short* __restrict__ Bp2,
                          short* __restrict__ Bp3, short* __restrict__ BpR){
  int tid = blockIdx.x * 256 + threadIdx.x;
  if (tid >= 112 * 512) return;
  int unit = tid >> 9;
  const float* Wrel; const float* root; short* Bp; int k32; int krel;
  if      (unit < 36){ Wrel = W1; root = r1; Bp = Bp1; k32 = unit;       krel = 1024; }
  else if (unit < 72){ Wrel = W2; root = r2; Bp = Bp2; k32 = unit - 36;  krel = 1024; }
  else if (unit <108){ Wrel = W3; root = r3; Bp = Bp3; k32 = unit - 72;  krel = 1024; }
  else               { Wrel = rw; root = rw; Bp = BpR; k32 = unit - 108; krel = 0;    }
  int lane = tid & 63;
  int nf   = (tid >> 6) & 7;
  int col  = nf * 16 + (lane & 15);
  short vals[8];
#pragma unroll
  for (int i = 0; i < 8; ++i){
    int kk = k32 * 32 + ((lane >> 4) << 3) + i;
    float f = (kk < krel) ? Wrel[(size_t)kk * 128 + col]
                          : root[(size_t)(kk - krel) * 128 + col];
    vals[i] = (short)f2bf(f);
  }
  *(bf16x8*)(Bp + (size_t)(k32 * 512 + (tid & 511)) * 8) = *(const bf16x8*)vals;
}

// ---------------- CSR build (relation-major: seg = r*NN + dst) -------------
__global__ void count_k(const int* __restrict__ dst, const int* __restrict__ et,
                        u32* __restrict__ cnt){
  int e = blockIdx.x * 256 + threadIdx.x;
  if (e >= EE) return;
  atomicAdd(&cnt[(size_t)et[e] * NN + dst[e]], 1u);
}

__global__ void scan1_k(const u32* __restrict__ cnt, u32* __restrict__ offs, u32* __restrict__ bsum){
  __shared__ u32 s[512];
  int t = threadIdx.x;                       // 256 threads
  int base = blockIdx.x * 1024 + t * 4;
  u32 loc[4]; u32 sum = 0;
#pragma unroll
  for (int i = 0; i < 4; ++i){ loc[i] = (base + i < NSEG) ? cnt[base + i] : 0u; sum += loc[i]; }
  int pb = 0;
  s[t] = sum; __syncthreads();
  for (int off = 1; off < 256; off <<= 1){
    u32 v = s[pb * 256 + t];
    if (t >= off) v += s[pb * 256 + t - off];
    s[(pb ^ 1) * 256 + t] = v; pb ^= 1; __syncthreads();
  }
  u32 incl = s[pb * 256 + t];
  u32 excl = incl - sum;
  if (t == 255) bsum[blockIdx.x] = incl;
  u32 run = excl;
#pragma unroll
  for (int i = 0; i < 4; ++i){ if (base + i < NSEG) offs[base + i] = run; run += loc[i]; }
}

__global__ void scan2_k(u32* __restrict__ bsum){
  __shared__ u32 s[1024];
  int t = threadIdx.x;                       // 512 threads
  u32 v = (t < NB_SCAN) ? bsum[t] : 0u;
  int pb = 0;
  s[t] = v; __syncthreads();
  for (int off = 1; off < 512; off <<= 1){
    u32 x = s[pb * 512 + t];
    if (t >= off) x += s[pb * 512 + t - off];
    s[(pb ^ 1) * 512 + t] = x; pb ^= 1; __syncthreads();
  }
  u32 incl = s[pb * 512 + t];
  if (t < NB_SCAN) bsum[t] = incl - v;       // exclusive
}

__global__ void scan3_k(u32* __restrict__ offs, const u32* __restrict__ bsum){
  int t = threadIdx.x;
  int base = blockIdx.x * 1024 + t * 4;
  u32 add = bsum[blockIdx.x];
#pragma unroll
  for (int i = 0; i < 4; ++i){ if (base + i < NSEG) offs[base + i] += add; }
  if (blockIdx.x == 0 && t == 0) offs[NSEG] = EE;
}

// fill: reuse cnt as cursor (atomicSub)
__global__ void fill_k(const int* __restrict__ src, const int* __restrict__ dst,
                       const int* __restrict__ et, const u32* __restrict__ offs,
                       u32* __restrict__ cnt, int* __restrict__ elist){
  int e = blockIdx.x * 256 + threadIdx.x;
  if (e >= EE) return;
  int s = et[e] * NN + dst[e];
  u32 p = atomicSub(&cnt[s], 1u);
  elist[offs[s] + p - 1] = src[e];
}

// ------- res projection + x->bf16 conversion fused --------------------------
// Reads x (f32) directly; each thread's 4 fragments are converted in-register
// (feeding both the MFMA and a one-time xb store — each (row,chunk) covered
// exactly once per grid). resb = bf16(x @ res_w + res_b); xb = bf16(x).
__launch_bounds__(256, 4)
__global__ void resg_k(const float* __restrict__ x, const short* __restrict__ Bp,
                       const float* __restrict__ rb, unsigned short* __restrict__ resb,
                       unsigned short* __restrict__ xb){
  const int tid = threadIdx.x;
  const int w = tid >> 6, l = tid & 63;
  const int sub = l >> 4, llr = l & 15;
  const int rowbase = blockIdx.x * 64 + w * 16;
  int vr = rowbase + llr; if (vr > NN - 1) vr = NN - 1;
  f32x4 acc[8] = {};
#pragma unroll
  for (int t = 0; t < 4; ++t){
    const float* xp = x + (size_t)vr * 128 + (t * 4 + sub) * 8;
    f32x4 fa = *(const f32x4*)xp;
    f32x4 fb = *(const f32x4*)(xp + 4);
    short vals[8];
    vals[0] = (short)f2bf(fa[0]); vals[1] = (short)f2bf(fa[1]);
    vals[2] = (short)f2bf(fa[2]); vals[3] = (short)f2bf(fa[3]);
    vals[4] = (short)f2bf(fb[0]); vals[5] = (short)f2bf(fb[1]);
    vals[6] = (short)f2bf(fb[2]); vals[7] = (short)f2bf(fb[3]);
    bf16x8 af = *(const bf16x8*)vals;
    *(bf16x8*)(xb + (size_t)vr * 128 + (t * 4 + sub) * 8) = af;   // once per (row,chunk)
    const short* bb = Bp + (size_t)(t * 8) * 512 + l * 8;
#pragma unroll
    for (int nf = 0; nf < 8; ++nf){
      bf16x8 bq = *(const bf16x8*)(bb + nf * 512);
      acc[nf] = __builtin_amdgcn_mfma_f32_16x16x32_bf16(af, bq, acc[nf], 0, 0, 0);
    }
  }
  const int lr = l >> 4, lc = l & 15;
#pragma unroll
  for (int nf = 0; nf < 8; ++nf){
    int col = nf * 16 + lc;
    float bv = rb[col];
#pragma unroll
    for (int r = 0; r < 4; ++r){
      int row = rowbase + lr * 4 + r;
      if (row < NN) resb[(size_t)row * 128 + col] = f2bf(acc[nf][r] + bv);
    }
  }
}

// ---- per-segment gather with 4-wide edge batching, packed f32x2 adds ------
#define ACC1(P0, P1) do{ \
  _Pragma("unroll") \
  for (int i_ = 0; i_ < 4; ++i_){ \
    f32x2 a_, b_; \
    a_[0] = __uint_as_float((P0)[i_] << 16); \
    a_[1] = __uint_as_float((P0)[i_] & 0xffff0000u); \
    b_[0] = __uint_as_float((P1)[i_] << 16); \
    b_[1] = __uint_as_float((P1)[i_] & 0xffff0000u); \
    s0[i_] += a_; s1[i_] += b_; \
  } }while(0)

__device__ __forceinline__ void gather_seg(u32 beg, u32 end,
                                           const unsigned short* __restrict__ hb,
                                           const int* __restrict__ elist,
                                           char* __restrict__ Ab,
                                           int row, int rseg, int ll8){
  f32x2 s0[4], s1[4];
#pragma unroll
  for (int i = 0; i < 4; ++i){ s0[i] = (f32x2){0.f,0.f}; s1[i] = (f32x2){0.f,0.f}; }
  u32 e = beg;
  for (; e + 4 <= end; e += 4){
    int q0 = elist[e], q1 = elist[e+1], q2 = elist[e+2], q3 = elist[e+3];
    const unsigned short* r0 = hb + (size_t)q0 * 128;
    const unsigned short* r1 = hb + (size_t)q1 * 128;
    const unsigned short* r2 = hb + (size_t)q2 * 128;
    const unsigned short* r3 = hb + (size_t)q3 * 128;
    u32x4 p00 = *(const u32x4*)r0, p01 = *(const u32x4*)(r0 + 8);
    u32x4 p10 = *(const u32x4*)r1, p11 = *(const u32x4*)(r1 + 8);
    u32x4 p20 = *(const u32x4*)r2, p21 = *(const u32x4*)(r2 + 8);
    u32x4 p30 = *(const u32x4*)r3, p31 = *(const u32x4*)(r3 + 8);
    ACC1(p00, p01); ACC1(p10, p11); ACC1(p20, p21); ACC1(p30, p31);
  }
  if (e + 2 <= end){
    int q0 = elist[e], q1 = elist[e+1];
    const unsigned short* r0 = hb + (size_t)q0 * 128;
    const unsigned short* r1 = hb + (size_t)q1 * 128;
    u32x4 p00 = *(const u32x4*)r0, p01 = *(const u32x4*)(r0 + 8);
    u32x4 p10 = *(const u32x4*)r1, p11 = *(const u32x4*)(r1 + 8);
    ACC1(p00, p01); ACC1(p10, p11);
    e += 2;
  }
  if (e < end){
    int q0 = elist[e];
    const unsigned short* r0 = hb + (size_t)q0 * 128;
    u32x4 p00 = *(const u32x4*)r0, p01 = *(const u32x4*)(r0 + 8);
    ACC1(p00, p01);
  }
  u32 deg = end - beg;
  if (deg){
    float inv = __builtin_amdgcn_rcpf((float)deg);
#pragma unroll
    for (int i = 0; i < 4; ++i){ s0[i] *= inv; s1[i] *= inv; }
  }
  u32x4 o0, o1;
#pragma unroll
  for (int i = 0; i < 4; ++i){
    o0[i] = (u32)f2bf(s0[i][0]) | ((u32)f2bf(s0[i][1]) << 16);
    o1[i] = (u32)f2bf(s1[i][0]) | ((u32)f2bf(s1[i][1]) << 16);
  }
  char* wp = Ab + row * RSTRIDE + (rseg * 16 + ll8 * 2) * 16;
  *(u32x4*)wp = o0;
  *(u32x4*)(wp + 16) = o1;
}

// -------- FUSED layer: BM=16, 512 threads, 4 BLOCKS/CU ---------------------
// LDS = 16 x 2320 B = 36.25 KB -> 4 resident blocks/CU. NN = 3125*16.
// Phase 1: root-row copy issued FIRST (loads in flight under the segment
// walks); 64 8-lane groups x 2 segments (same row, relations r and r+4).
// Phase 2: 8 waves, wave w=nf: 1 ds_read + 1 B load + 1 MFMA per (kt,t).
template<int OUTMODE>
__launch_bounds__(512, 4)
__global__ void fused_k(const u32* __restrict__ offs, const int* __restrict__ elist,
                        const unsigned short* __restrict__ h,
                        const short* __restrict__ Bp,
                        const float* __restrict__ bias,
                        const unsigned short* __restrict__ resb,
                        float* __restrict__ outf, unsigned short* __restrict__ outb){
  __shared__ char Ab[16 * RSTRIDE];          // 36.25 KB
  const int tid = threadIdx.x;
  const int mbase = blockIdx.x * 16;

  // ---------- phase 1: gather ----------
  {
    const int g = tid >> 3, ll8 = tid & 7;
    const unsigned short* hb = h + (size_t)ll8 * 16;
    if (g < 16){                             // root row copy FIRST, slots 128..143
      const unsigned short* rp = h + (size_t)(mbase + g) * 128 + ll8 * 16;
      u32x4 o0 = *(const u32x4*)rp, o1 = *(const u32x4*)(rp + 8);
      char* wp = Ab + g * RSTRIDE + (128 + ll8 * 2) * 16;
      *(u32x4*)wp = o0;
      *(u32x4*)(wp + 16) = o1;
    }
    int r0 = g >> 4, row = g & 15;           // task0: relation r0, row
    int r1 = r0 + 4;                         // task1: relation r0+4, same row
    int v = mbase + row;                     // always < NN (3125*16 exact)
    size_t sg0 = (size_t)r0 * NN + v, sg1 = (size_t)r1 * NN + v;
    u32 b0 = offs[sg0], e0 = offs[sg0 + 1];
    u32 b1 = offs[sg1], e1 = offs[sg1 + 1];
    gather_seg(b0, e0, hb, elist, Ab, row, r0, ll8);
    gather_seg(b1, e1, hb, elist, Ab, row, r1, ll8);
  }
  __syncthreads();

  // ---------- phase 2: GEMM (8 waves) ----------
  const int w = tid >> 6, l = tid & 63;
  const int nf = w;
  const int sub = l >> 4, llr = l & 15;
  f32x4 acc = {};
#pragma unroll 6
  for (int kt = 0; kt < 18; ++kt){
#pragma unroll
    for (int t = 0; t < 2; ++t){
      int ks = kt * 8 + t * 4 + sub;
      bf16x8 af = *(const bf16x8*)(Ab + llr * RSTRIDE + ks * 16);
      bf16x8 bq = *(const bf16x8*)(Bp + ((size_t)((kt * 2 + t) * 8 + nf)) * 512 + l * 8);
      acc = __builtin_amdgcn_mfma_f32_16x16x32_bf16(af, bq, acc, 0, 0, 0);
    }
  }

  // ---------- epilogue ----------
  const int lr = l >> 4, lc = l & 15;
  int col = nf * 16 + lc;
  float bv = bias[col];
#pragma unroll
  for (int r = 0; r < 4; ++r){
    int row = mbase + lr * 4 + r;
    float v = acc[r] + bv;
    v = bf2f(resb[(size_t)row * 128 + col]) + fmaxf(v, 0.f);
    if (OUTMODE == 1) outb[(size_t)row * 128 + col] = f2bf(v);
    else              outf[(size_t)row * 128 + col] = v;
  }
}

extern "C" void kernel_launch(void* const* d_in, const int* in_sizes, int n_in,
                              void* d_out, int out_size, void* d_ws, size_t ws_size,
                              hipStream_t stream){
  const float* x  = (const float*)d_in[0];
  const int*   ei = (const int*)d_in[1];
  const int*   et = (const int*)d_in[2];
  const float* W1 = (const float*)d_in[3];
  const float* r1 = (const float*)d_in[4];
  const float* b1 = (const float*)d_in[5];
  const float* W2 = (const float*)d_in[6];
  const float* r2 = (const float*)d_in[7];
  const float* b2 = (const float*)d_in[8];
  const float* W3 = (const float*)d_in[9];
  const float* r3 = (const float*)d_in[10];
  const float* b3 = (const float*)d_in[11];
  const float* rw = (const float*)d_in[12];
  const float* rb = (const float*)d_in[13];
  const int* srcv = ei;
  const int* dstv = ei + EE;

  char* p = (char*)d_ws;
  auto take = [&](size_t b)->char*{ char* q = p; p += (b + 255) & ~(size_t)255; return q; };
  unsigned short* xb   = (unsigned short*)take((size_t)NN * 128 * 2);
  unsigned short* h1   = (unsigned short*)take((size_t)NN * 128 * 2);
  unsigned short* h2   = (unsigned short*)take((size_t)NN * 128 * 2);
  unsigned short* resb = (unsigned short*)take((size_t)NN * 128 * 2);
  short* Bp1 = (short*)take(36 * 4096 * 2);
  short* Bp2 = (short*)take(36 * 4096 * 2);
  short* Bp3 = (short*)take(36 * 4096 * 2);
  short* BpR = (short*)take(4 * 4096 * 2);
  u32* cnt   = (u32*)take((size_t)NSEG * 4);
  u32* offs  = (u32*)take((size_t)(NSEG + 1) * 4);
  int* elist = (int*)take((size_t)EE * 4);
  u32* bsum  = (u32*)take((size_t)NB_SCAN * 4);

  hipMemsetAsync(cnt, 0, (size_t)NSEG * 4, stream);

  // weight packing (once)
  packall_k<<<(112 * 512 + 255) / 256, 256, 0, stream>>>(W1, r1, W2, r2, W3, r3, rw,
                                                         Bp1, Bp2, Bp3, BpR);

  // CSR over segments (etype*NN + dst), once for all layers
  count_k<<<(EE + 255) / 256, 256, 0, stream>>>(dstv, et, cnt);
  scan1_k<<<NB_SCAN, 256, 0, stream>>>(cnt, offs, bsum);
  scan2_k<<<1, 512, 0, stream>>>(bsum);
  scan3_k<<<NB_SCAN, 256, 0, stream>>>(offs, bsum);
  fill_k<<<(EE + 255) / 256, 256, 0, stream>>>(srcv, dstv, et, offs, cnt, elist);

  const int GB = NN / 16;  // 3125

  // res = bf16(x @ res_w + res_b); also emits xb = bf16(x)
  resg_k<<<(NN + 63) / 64, 256, 0, stream>>>(x, BpR, rb, resb, xb);

  // fused layers
  fused_k<1><<<GB, 512, 0, stream>>>(offs, elist, xb, Bp1, b1, resb, nullptr, h1);
  fused_k<1><<<GB, 512, 0, stream>>>(offs, elist, h1, Bp2, b2, resb, nullptr, h2);
  fused_k<2><<<GB, 512, 0, stream>>>(offs, elist, h2, Bp3, b3, resb, (float*)d_out, nullptr);
}